// Round 1
// baseline (488.173 us; speedup 1.0000x reference)
//
#include <hip/hip_runtime.h>

typedef unsigned short u16;
typedef unsigned int   u32;

typedef short bf16x8 __attribute__((ext_vector_type(8)));
typedef float f32x4  __attribute__((ext_vector_type(4)));

__device__ __forceinline__ float bf2f(u16 u) { return __uint_as_float(((u32)u) << 16); }
__device__ __forceinline__ u16 f2bf(float f) {
    u32 u = __float_as_uint(f);
    return (u16)((u + 0x7fffu + ((u >> 16) & 1u)) >> 16);
}

#define MFMA16(a, b, c) __builtin_amdgcn_mfma_f32_16x16x32_bf16(a, b, c, 0, 0, 0)

// ---------------------------------------------------------------------------
// K1: qkv 1x1 conv.  out1[b][co<384][h][w] (bf16) = sum_ci W[co][ci]*x[b][ci][h][w] + b[co]
// One block per (h, b): GEMM M=384, N=128 (one row of pixels), K=128.
// ---------------------------------------------------------------------------
__global__ __launch_bounds__(512, 1) void k_qkv(const float* __restrict__ x,
                                                const float* __restrict__ w,
                                                const float* __restrict__ bias,
                                                u16* __restrict__ out1) {
    extern __shared__ char smem[];
    u16* xT = (u16*)smem;        // [128 p][136] bf16 (x transposed: xT[p][ci])
    u16* Cs = xT + 128 * 136;    // [384 co][136] bf16 staging
    const int h = blockIdx.x, b = blockIdx.y;
    const int t = threadIdx.x;

    const float* xb = x + (((size_t)(b * 128)) << 14) + (h << 7);
    for (int it = 0; it < 32; ++it) {
        int idx = it * 512 + t;
        int ci = idx >> 7, p = idx & 127;
        xT[p * 136 + ci] = f2bf(xb[((size_t)ci << 14) + p]);
    }
    __syncthreads();

    const int wave = t >> 6, lane = t & 63, m16 = lane & 15, quad = lane >> 4;
    f32x4 acc[3][8] = {};
    for (int kk = 0; kk < 4; ++kk) {
        const int kb = kk * 32 + quad * 8;
        bf16x8 afr[3];
#pragma unroll
        for (int mt = 0; mt < 3; ++mt) {
            const float* wp = w + (wave * 48 + mt * 16 + m16) * 128 + kb;
            float4 w0 = *(const float4*)wp;
            float4 w1 = *(const float4*)(wp + 4);
            bf16x8 a;
            a[0] = (short)f2bf(w0.x); a[1] = (short)f2bf(w0.y);
            a[2] = (short)f2bf(w0.z); a[3] = (short)f2bf(w0.w);
            a[4] = (short)f2bf(w1.x); a[5] = (short)f2bf(w1.y);
            a[6] = (short)f2bf(w1.z); a[7] = (short)f2bf(w1.w);
            afr[mt] = a;
        }
#pragma unroll
        for (int nt = 0; nt < 8; ++nt) {
            bf16x8 bfr = *(const bf16x8*)(&xT[(nt * 16 + m16) * 136 + kb]);
            acc[0][nt] = MFMA16(afr[0], bfr, acc[0][nt]);
            acc[1][nt] = MFMA16(afr[1], bfr, acc[1][nt]);
            acc[2][nt] = MFMA16(afr[2], bfr, acc[2][nt]);
        }
    }
    float bco[3][4];
#pragma unroll
    for (int mt = 0; mt < 3; ++mt)
#pragma unroll
        for (int r = 0; r < 4; ++r) bco[mt][r] = bias[wave * 48 + mt * 16 + quad * 4 + r];
#pragma unroll
    for (int mt = 0; mt < 3; ++mt)
#pragma unroll
        for (int nt = 0; nt < 8; ++nt) {
            int p = nt * 16 + m16;
#pragma unroll
            for (int r = 0; r < 4; ++r)
                Cs[(wave * 48 + mt * 16 + quad * 4 + r) * 136 + p] = f2bf(acc[mt][nt][r] + bco[mt][r]);
        }
    __syncthreads();

    u16* ob = out1 + (((size_t)(b * 384)) << 14) + (h << 7);
    for (int it = 0; it < 12; ++it) {
        int idx = it * 512 + t;
        int co = idx >> 4, cp = idx & 15;
        *(uint4*)(&ob[((size_t)co << 14) + cp * 8]) = *(const uint4*)(&Cs[co * 136 + cp * 8]);
    }
}

// ---------------------------------------------------------------------------
// K2: depthwise 3x3, zero pad, + bias.  in/out bf16 [8][384][128][128]
// ---------------------------------------------------------------------------
__global__ __launch_bounds__(256, 4) void k_dw(const u16* __restrict__ in,
                                               const float* __restrict__ w,
                                               const float* __restrict__ bias,
                                               u16* __restrict__ out) {
    const int htile = blockIdx.x;   // 0..63
    const int ch = blockIdx.y;      // 0..383
    const int b = blockIdx.z;       // 0..7
    const int t = threadIdx.x;
    const int wv = t & 127, hh = htile * 2 + (t >> 7);
    const u16* base = in + (((size_t)(b * 384 + ch)) << 14);
    float wg[9];
#pragma unroll
    for (int i = 0; i < 9; ++i) wg[i] = w[ch * 9 + i];
    float acc = bias[ch];
#pragma unroll
    for (int dy = -1; dy <= 1; ++dy) {
        int y = hh + dy;
        if (y < 0 || y > 127) continue;
#pragma unroll
        for (int dx = -1; dx <= 1; ++dx) {
            int xx = wv + dx;
            if (xx < 0 || xx > 127) continue;
            acc += wg[(dy + 1) * 3 + dx + 1] * bf2f(base[(y << 7) + xx]);
        }
    }
    out[(((size_t)(b * 384 + ch)) << 14) + (hh << 7) + wv] = f2bf(acc);
}

// ---------------------------------------------------------------------------
// K3: per-(b,head,c) attention. One block per (ch, b), 512 threads / 8 waves.
//   S[j,k] = sum_i Q[i,j]K[i,k] * temp * rq[j] * rk[k]; softmax over j;
//   O[i,k] = sum_j V[i,j] P[j,k].
// LDS: Qt[128][136] Kt[128][136] Vs[128][136] Pt[128][136] bf16 + rq/rk f32.
// St f32[128][132] and Osh bf16[128][136] alias the (dead) Qt/Kt region.
// ---------------------------------------------------------------------------
__global__ __launch_bounds__(512, 1) void k_attn(const u16* __restrict__ qkv,
                                                 const float* __restrict__ temp,
                                                 u16* __restrict__ outp) {
    extern __shared__ char smem[];
    u16* Qt = (u16*)smem;           // [128 j][136 i]
    u16* Kt = Qt + 128 * 136;       // [128 k][136 i]
    u16* Vs = Kt + 128 * 136;       // [128 i][136 j]
    u16* Pt = Vs + 128 * 136;       // [128 k][136 j]
    float* rq = (float*)(Pt + 128 * 136);  // [128]
    float* rk = rq + 128;                  // [128]
    float* St = (float*)smem;       // [128 k][132 j]  (aliases Qt/Kt)
    u16* Osh = (u16*)smem;          // [128 i][136 k]  (aliases)

    const int ch = blockIdx.x, b = blockIdx.y;
    const int head = ch >> 5;
    const int t = threadIdx.x;
    const size_t qoff = ((size_t)(b * 384 + ch)) << 14;
    const size_t koff = ((size_t)(b * 384 + 128 + ch)) << 14;
    const size_t voff = ((size_t)(b * 384 + 256 + ch)) << 14;

    // --- load V (natural layout, vectorized), Q/K (transposed) ---
    for (int it = 0; it < 4; ++it) {
        int idx = it * 512 + t;
        int row = idx >> 4, cp = idx & 15;
        *(uint4*)(&Vs[row * 136 + cp * 8]) = *(const uint4*)(&qkv[voff + (row << 7) + cp * 8]);
    }
    for (int it = 0; it < 32; ++it) {
        int idx = it * 512 + t;
        int i = idx >> 7, j = idx & 127;
        Qt[j * 136 + i] = qkv[qoff + (i << 7) + j];
        Kt[j * 136 + i] = qkv[koff + (i << 7) + j];
    }
    __syncthreads();

    // --- column norms over i (rows of Qt/Kt) ---
    if (t < 256) {
        const u16* rowp = (t < 128) ? &Qt[t * 136] : &Kt[(t - 128) * 136];
        float s = 0.f;
#pragma unroll
        for (int c = 0; c < 16; ++c) {
            uint4 v = *(const uint4*)(rowp + c * 8);
            float f0 = bf2f((u16)(v.x & 0xffff)), f1 = bf2f((u16)(v.x >> 16));
            float f2 = bf2f((u16)(v.y & 0xffff)), f3 = bf2f((u16)(v.y >> 16));
            float f4 = bf2f((u16)(v.z & 0xffff)), f5 = bf2f((u16)(v.z >> 16));
            float f6 = bf2f((u16)(v.w & 0xffff)), f7 = bf2f((u16)(v.w >> 16));
            s += f0 * f0 + f1 * f1 + f2 * f2 + f3 * f3 + f4 * f4 + f5 * f5 + f6 * f6 + f7 * f7;
        }
        float r = 1.0f / fmaxf(sqrtf(s), 1e-12f);
        if (t < 128) rq[t] = r; else rk[t - 128] = r;
    }
    __syncthreads();

    const int wave = t >> 6, lane = t & 63, m16 = lane & 15, quad = lane >> 4;

    // --- matmul1: S = Q^T K  (wave owns j-tile = wave*16..+15, all 8 k-tiles) ---
    f32x4 acc[8] = {};
    for (int kk = 0; kk < 4; ++kk) {
        const int kb = kk * 32 + quad * 8;
        bf16x8 a = *(const bf16x8*)(&Qt[(wave * 16 + m16) * 136 + kb]);
#pragma unroll
        for (int nt = 0; nt < 8; ++nt) {
            bf16x8 bf = *(const bf16x8*)(&Kt[(nt * 16 + m16) * 136 + kb]);
            acc[nt] = MFMA16(a, bf, acc[nt]);
        }
    }
    const float tv = temp[head];
    float rqv[4];
#pragma unroll
    for (int r = 0; r < 4; ++r) rqv[r] = rq[wave * 16 + quad * 4 + r] * tv;
    __syncthreads();  // all Qt/Kt reads done -> safe to overwrite region with St
#pragma unroll
    for (int nt = 0; nt < 8; ++nt) {
        int kcol = nt * 16 + m16;
        float rkv = rk[kcol];
        f32x4 v = acc[nt], o;
        o[0] = v[0] * rqv[0] * rkv; o[1] = v[1] * rqv[1] * rkv;
        o[2] = v[2] * rqv[2] * rkv; o[3] = v[3] * rqv[3] * rkv;
        *(f32x4*)(&St[kcol * 132 + wave * 16 + quad * 4]) = o;
    }
    __syncthreads();

    // --- softmax over j, per column k.  4 threads per column. ---
    {
        const int col = t >> 2, part = t & 3;
        const float* Srow = &St[col * 132 + part * 32];
        float e[32];
#pragma unroll
        for (int c = 0; c < 8; ++c) {
            f32x4 v = *(const f32x4*)(&Srow[c * 4]);
            e[c * 4 + 0] = v[0]; e[c * 4 + 1] = v[1]; e[c * 4 + 2] = v[2]; e[c * 4 + 3] = v[3];
        }
        float lmax = -1e30f;
#pragma unroll
        for (int jj = 0; jj < 32; ++jj) lmax = fmaxf(lmax, e[jj]);
        lmax = fmaxf(lmax, __shfl_xor(lmax, 1));
        lmax = fmaxf(lmax, __shfl_xor(lmax, 2));
        float lsum = 0.f;
#pragma unroll
        for (int jj = 0; jj < 32; ++jj) { e[jj] = __expf(e[jj] - lmax); lsum += e[jj]; }
        lsum += __shfl_xor(lsum, 1);
        lsum += __shfl_xor(lsum, 2);
        float inv = 1.0f / lsum;
        u32* prow = (u32*)&Pt[col * 136 + part * 32];
#pragma unroll
        for (int c2 = 0; c2 < 16; ++c2) {
            u32 lo = f2bf(e[2 * c2] * inv), hi = f2bf(e[2 * c2 + 1] * inv);
            prow[c2] = lo | (hi << 16);
        }
    }
    __syncthreads();

    // --- matmul2: O = V * P  (wave owns i-tile = wave*16..+15) ---
    f32x4 acc2[8] = {};
    for (int kk = 0; kk < 4; ++kk) {
        const int kb = kk * 32 + quad * 8;
        bf16x8 a = *(const bf16x8*)(&Vs[(wave * 16 + m16) * 136 + kb]);
#pragma unroll
        for (int nt = 0; nt < 8; ++nt) {
            bf16x8 bf = *(const bf16x8*)(&Pt[(nt * 16 + m16) * 136 + kb]);
            acc2[nt] = MFMA16(a, bf, acc2[nt]);
        }
    }
#pragma unroll
    for (int nt = 0; nt < 8; ++nt) {
        int kcol = nt * 16 + m16;
#pragma unroll
        for (int r = 0; r < 4; ++r)
            Osh[(wave * 16 + quad * 4 + r) * 136 + kcol] = f2bf(acc2[nt][r]);
    }
    __syncthreads();

    u16* ob = outp + (((size_t)(b * 128 + ch)) << 14);
    for (int it = 0; it < 4; ++it) {
        int idx = it * 512 + t;
        int row = idx >> 4, cp = idx & 15;
        *(uint4*)(&ob[(row << 7) + cp * 8]) = *(const uint4*)(&Osh[row * 136 + cp * 8]);
    }
}

// ---------------------------------------------------------------------------
// K4: proj 1x1 conv.  out[b][co<128][h][w] (fp32) = sum_ci W[co][ci]*ain[b][ci][h][w] + b[co]
// ---------------------------------------------------------------------------
__global__ __launch_bounds__(512, 1) void k_proj(const u16* __restrict__ ain,
                                                 const float* __restrict__ w,
                                                 const float* __restrict__ bias,
                                                 float* __restrict__ outp) {
    extern __shared__ char smem[];
    u16* xT = (u16*)smem;               // [128 p][136 ci]
    float* Cs = (float*)(xT + 128 * 136);  // [128 co][132 p]
    const int h = blockIdx.x, b = blockIdx.y;
    const int t = threadIdx.x;

    const u16* ab = ain + (((size_t)(b * 128)) << 14) + (h << 7);
    for (int it = 0; it < 32; ++it) {
        int idx = it * 512 + t;
        int ci = idx >> 7, p = idx & 127;
        xT[p * 136 + ci] = ab[((size_t)ci << 14) + p];
    }
    __syncthreads();

    const int wave = t >> 6, lane = t & 63, m16 = lane & 15, quad = lane >> 4;
    f32x4 acc[8] = {};
    for (int kk = 0; kk < 4; ++kk) {
        const int kb = kk * 32 + quad * 8;
        const float* wp = w + (wave * 16 + m16) * 128 + kb;
        float4 w0 = *(const float4*)wp;
        float4 w1 = *(const float4*)(wp + 4);
        bf16x8 a;
        a[0] = (short)f2bf(w0.x); a[1] = (short)f2bf(w0.y);
        a[2] = (short)f2bf(w0.z); a[3] = (short)f2bf(w0.w);
        a[4] = (short)f2bf(w1.x); a[5] = (short)f2bf(w1.y);
        a[6] = (short)f2bf(w1.z); a[7] = (short)f2bf(w1.w);
#pragma unroll
        for (int nt = 0; nt < 8; ++nt) {
            bf16x8 bf = *(const bf16x8*)(&xT[(nt * 16 + m16) * 136 + kb]);
            acc[nt] = MFMA16(a, bf, acc[nt]);
        }
    }
    float bv[4];
#pragma unroll
    for (int r = 0; r < 4; ++r) bv[r] = bias[wave * 16 + quad * 4 + r];
#pragma unroll
    for (int nt = 0; nt < 8; ++nt) {
        int p = nt * 16 + m16;
#pragma unroll
        for (int r = 0; r < 4; ++r)
            Cs[(wave * 16 + quad * 4 + r) * 132 + p] = acc[nt][r] + bv[r];
    }
    __syncthreads();

    float* ob = outp + (((size_t)(b * 128)) << 14) + (h << 7);
    for (int it = 0; it < 8; ++it) {
        int idx = it * 512 + t;
        int row = idx >> 5, cp = idx & 31;
        *(float4*)(&ob[((size_t)row << 14) + cp * 4]) = *(const float4*)(&Cs[row * 132 + cp * 4]);
    }
}

// ---------------------------------------------------------------------------
extern "C" void kernel_launch(void* const* d_in, const int* in_sizes, int n_in,
                              void* d_out, int out_size, void* d_ws, size_t ws_size,
                              hipStream_t stream) {
    const float* x      = (const float*)d_in[0];
    const float* qkv_w  = (const float*)d_in[1];
    const float* qkv_b  = (const float*)d_in[2];
    const float* dw_w   = (const float*)d_in[3];
    const float* dw_b   = (const float*)d_in[4];
    const float* proj_w = (const float*)d_in[5];
    const float* proj_b = (const float*)d_in[6];
    const float* temp   = (const float*)d_in[7];
    float* out = (float*)d_out;

    // ws layout: buf1 [8*384*16384] bf16 (conv-out, later reused for attn-out)
    //            buf2 [8*384*16384] bf16 (qkv post-dw)   -> 192 MB total
    u16* buf1 = (u16*)d_ws;
    u16* buf2 = buf1 + (size_t)8 * 384 * 16384;

    hipFuncSetAttribute((const void*)k_qkv,  hipFuncAttributeMaxDynamicSharedMemorySize, 139264);
    hipFuncSetAttribute((const void*)k_attn, hipFuncAttributeMaxDynamicSharedMemorySize, 140288);
    hipFuncSetAttribute((const void*)k_proj, hipFuncAttributeMaxDynamicSharedMemorySize, 102400);

    k_qkv<<<dim3(128, 8), 512, 139264, stream>>>(x, qkv_w, qkv_b, buf1);
    k_dw<<<dim3(64, 384, 8), 256, 0, stream>>>(buf1, dw_w, dw_b, buf2);
    k_attn<<<dim3(128, 8), 512, 140288, stream>>>(buf2, temp, buf1);
    k_proj<<<dim3(128, 8), 512, 102400, stream>>>(buf1, proj_w, proj_b, out);
}

// Round 2
// 279.504 us; speedup vs baseline: 1.7466x; 1.7466x over previous
//
#include <hip/hip_runtime.h>

typedef unsigned short u16;
typedef unsigned int   u32;

typedef short bf16x8 __attribute__((ext_vector_type(8)));
typedef float f32x4  __attribute__((ext_vector_type(4)));

__device__ __forceinline__ float bf2f(u16 u) { return __uint_as_float(((u32)u) << 16); }
__device__ __forceinline__ u16 f2bf(float f) {
    u32 u = __float_as_uint(f);
    return (u16)((u + 0x7fffu + ((u >> 16) & 1u)) >> 16);
}

#define MFMA16(a, b, c) __builtin_amdgcn_mfma_f32_16x16x32_bf16(a, b, c, 0, 0, 0)

// ---------------------------------------------------------------------------
// K1: qkv 1x1 conv.  out1[b][co<384][h][w] (bf16) = sum_ci W[co][ci]*x[b][ci][h][w] + b[co]
// One block per (h, b): GEMM M=384, N=128 (one row of pixels), K=128.
// ---------------------------------------------------------------------------
__global__ __launch_bounds__(512, 1) void k_qkv(const float* __restrict__ x,
                                                const float* __restrict__ w,
                                                const float* __restrict__ bias,
                                                u16* __restrict__ out1) {
    extern __shared__ char smem[];
    u16* xT = (u16*)smem;        // [128 p][136] bf16 (x transposed: xT[p][ci])
    u16* Cs = xT + 128 * 136;    // [384 co][136] bf16 staging
    const int h = blockIdx.x, b = blockIdx.y;
    const int t = threadIdx.x;

    const float* xb = x + (((size_t)(b * 128)) << 14) + (h << 7);
    for (int it = 0; it < 32; ++it) {
        int idx = it * 512 + t;
        int ci = idx >> 7, p = idx & 127;
        xT[p * 136 + ci] = f2bf(xb[((size_t)ci << 14) + p]);
    }
    __syncthreads();

    const int wave = t >> 6, lane = t & 63, m16 = lane & 15, quad = lane >> 4;
    f32x4 acc[3][8] = {};
    for (int kk = 0; kk < 4; ++kk) {
        const int kb = kk * 32 + quad * 8;
        bf16x8 afr[3];
#pragma unroll
        for (int mt = 0; mt < 3; ++mt) {
            const float* wp = w + (wave * 48 + mt * 16 + m16) * 128 + kb;
            float4 w0 = *(const float4*)wp;
            float4 w1 = *(const float4*)(wp + 4);
            bf16x8 a;
            a[0] = (short)f2bf(w0.x); a[1] = (short)f2bf(w0.y);
            a[2] = (short)f2bf(w0.z); a[3] = (short)f2bf(w0.w);
            a[4] = (short)f2bf(w1.x); a[5] = (short)f2bf(w1.y);
            a[6] = (short)f2bf(w1.z); a[7] = (short)f2bf(w1.w);
            afr[mt] = a;
        }
#pragma unroll
        for (int nt = 0; nt < 8; ++nt) {
            bf16x8 bfr = *(const bf16x8*)(&xT[(nt * 16 + m16) * 136 + kb]);
            acc[0][nt] = MFMA16(afr[0], bfr, acc[0][nt]);
            acc[1][nt] = MFMA16(afr[1], bfr, acc[1][nt]);
            acc[2][nt] = MFMA16(afr[2], bfr, acc[2][nt]);
        }
    }
    float bco[3][4];
#pragma unroll
    for (int mt = 0; mt < 3; ++mt)
#pragma unroll
        for (int r = 0; r < 4; ++r) bco[mt][r] = bias[wave * 48 + mt * 16 + quad * 4 + r];
#pragma unroll
    for (int mt = 0; mt < 3; ++mt)
#pragma unroll
        for (int nt = 0; nt < 8; ++nt) {
            int p = nt * 16 + m16;
#pragma unroll
            for (int r = 0; r < 4; ++r)
                Cs[(wave * 48 + mt * 16 + quad * 4 + r) * 136 + p] = f2bf(acc[mt][nt][r] + bco[mt][r]);
        }
    __syncthreads();

    u16* ob = out1 + (((size_t)(b * 384)) << 14) + (h << 7);
    for (int it = 0; it < 12; ++it) {
        int idx = it * 512 + t;
        int co = idx >> 4, cp = idx & 15;
        *(uint4*)(&ob[((size_t)co << 14) + cp * 8]) = *(const uint4*)(&Cs[co * 136 + cp * 8]);
    }
}

// ---------------------------------------------------------------------------
// K2: depthwise 3x3, zero pad, + bias.  in/out bf16 [8][384][128][128]
// LDS-tiled: block = (htile of 32 rows, ch, b). Stage 34 rows x 128 cols
// (+halo guards) as bf16 in LDS via uint4 loads; each thread computes
// 2 rows x 8 cols in fp32 and stores packed uint4.
// ---------------------------------------------------------------------------
__global__ __launch_bounds__(256, 4) void k_dw(const u16* __restrict__ in,
                                               const float* __restrict__ w,
                                               const float* __restrict__ bias,
                                               u16* __restrict__ out) {
    // row stride 144: guard [0..7] = cols -8..-1, data [8..135] = cols 0..127,
    // guard [136..143] = cols 128..135. uint4-aligned everywhere.
    __shared__ u16 tile[34 * 144];
    const int htile = blockIdx.x;   // 0..3 -> rows htile*32 .. +31
    const int ch = blockIdx.y;      // 0..383
    const int b = blockIdx.z;       // 0..7
    const int t = threadIdx.x;
    const u16* base = in + (((size_t)(b * 384 + ch)) << 14);

    // zero guards: 34 rows x 2 guard-uint4
    if (t < 68) {
        int r = t >> 1, side = t & 1;
        uint4 z = {0, 0, 0, 0};
        *(uint4*)(&tile[r * 144 + side * 136]) = z;
    }
    // main load: 34 rows x 16 uint4, zero-fill out-of-image rows
    for (int it = 0; it < 3; ++it) {
        int idx = it * 256 + t;
        if (idx < 544) {
            int r = idx >> 4, cq = idx & 15;
            int y = htile * 32 - 1 + r;
            uint4 v = {0, 0, 0, 0};
            if (y >= 0 && y <= 127) v = *(const uint4*)(base + (y << 7) + cq * 8);
            *(uint4*)(&tile[r * 144 + 8 + cq * 8]) = v;
        }
    }
    float wg[9];
#pragma unroll
    for (int i = 0; i < 9; ++i) wg[i] = w[ch * 9 + i];
    const float bv = bias[ch];
    __syncthreads();

    const int r = t >> 4, cp = t & 15, c0 = cp * 8;
    u16* ob = out + (((size_t)(b * 384 + ch)) << 14) + ((htile * 32) << 7) + c0;
#pragma unroll
    for (int half = 0; half < 2; ++half) {
        const int ro = r + half * 16;  // local output row 0..31
        float acc[8];
#pragma unroll
        for (int c = 0; c < 8; ++c) acc[c] = bv;
#pragma unroll
        for (int dy = 0; dy < 3; ++dy) {
            const u16* row = &tile[(ro + dy) * 144 + 8 + c0];
            float v[10];
            v[0] = bf2f(row[-1]);
            uint4 m = *(const uint4*)row;
            v[1] = bf2f((u16)(m.x & 0xffff)); v[2] = bf2f((u16)(m.x >> 16));
            v[3] = bf2f((u16)(m.y & 0xffff)); v[4] = bf2f((u16)(m.y >> 16));
            v[5] = bf2f((u16)(m.z & 0xffff)); v[6] = bf2f((u16)(m.z >> 16));
            v[7] = bf2f((u16)(m.w & 0xffff)); v[8] = bf2f((u16)(m.w >> 16));
            v[9] = bf2f(row[8]);
#pragma unroll
            for (int dx = 0; dx < 3; ++dx) {
                const float wv = wg[dy * 3 + dx];
#pragma unroll
                for (int c = 0; c < 8; ++c) acc[c] += wv * v[c + dx];
            }
        }
        u32 pk[4];
#pragma unroll
        for (int c2 = 0; c2 < 4; ++c2) {
            u32 lo = f2bf(acc[2 * c2]), hi = f2bf(acc[2 * c2 + 1]);
            pk[c2] = lo | (hi << 16);
        }
        *(uint4*)(ob + (ro << 7)) = *(uint4*)pk;
    }
}

// ---------------------------------------------------------------------------
// K3: per-(b,head,c) attention. One block per (ch, b), 512 threads / 8 waves.
//   S[j,k] = sum_i Q[i,j]K[i,k] * temp * rq[j] * rk[k]; softmax over j;
//   O[i,k] = sum_j V[i,j] P[j,k].
// LDS: Qt[128][136] Kt[128][136] Vs[128][136] Pt[128][136] bf16 + rq/rk f32.
// St f32[128][132] and Osh bf16[128][136] alias the (dead) Qt/Kt region.
// ---------------------------------------------------------------------------
__global__ __launch_bounds__(512, 1) void k_attn(const u16* __restrict__ qkv,
                                                 const float* __restrict__ temp,
                                                 u16* __restrict__ outp) {
    extern __shared__ char smem[];
    u16* Qt = (u16*)smem;           // [128 j][136 i]
    u16* Kt = Qt + 128 * 136;       // [128 k][136 i]
    u16* Vs = Kt + 128 * 136;       // [128 i][136 j]
    u16* Pt = Vs + 128 * 136;       // [128 k][136 j]
    float* rq = (float*)(Pt + 128 * 136);  // [128]
    float* rk = rq + 128;                  // [128]
    float* St = (float*)smem;       // [128 k][132 j]  (aliases Qt/Kt)
    u16* Osh = (u16*)smem;          // [128 i][136 k]  (aliases)

    const int ch = blockIdx.x, b = blockIdx.y;
    const int head = ch >> 5;
    const int t = threadIdx.x;
    const size_t qoff = ((size_t)(b * 384 + ch)) << 14;
    const size_t koff = ((size_t)(b * 384 + 128 + ch)) << 14;
    const size_t voff = ((size_t)(b * 384 + 256 + ch)) << 14;

    // --- load V (natural layout, vectorized), Q/K (transposed) ---
    for (int it = 0; it < 4; ++it) {
        int idx = it * 512 + t;
        int row = idx >> 4, cp = idx & 15;
        *(uint4*)(&Vs[row * 136 + cp * 8]) = *(const uint4*)(&qkv[voff + (row << 7) + cp * 8]);
    }
    for (int it = 0; it < 32; ++it) {
        int idx = it * 512 + t;
        int i = idx >> 7, j = idx & 127;
        Qt[j * 136 + i] = qkv[qoff + (i << 7) + j];
        Kt[j * 136 + i] = qkv[koff + (i << 7) + j];
    }
    __syncthreads();

    // --- column norms over i (rows of Qt/Kt) ---
    if (t < 256) {
        const u16* rowp = (t < 128) ? &Qt[t * 136] : &Kt[(t - 128) * 136];
        float s = 0.f;
#pragma unroll
        for (int c = 0; c < 16; ++c) {
            uint4 v = *(const uint4*)(rowp + c * 8);
            float f0 = bf2f((u16)(v.x & 0xffff)), f1 = bf2f((u16)(v.x >> 16));
            float f2 = bf2f((u16)(v.y & 0xffff)), f3 = bf2f((u16)(v.y >> 16));
            float f4 = bf2f((u16)(v.z & 0xffff)), f5 = bf2f((u16)(v.z >> 16));
            float f6 = bf2f((u16)(v.w & 0xffff)), f7 = bf2f((u16)(v.w >> 16));
            s += f0 * f0 + f1 * f1 + f2 * f2 + f3 * f3 + f4 * f4 + f5 * f5 + f6 * f6 + f7 * f7;
        }
        float r = 1.0f / fmaxf(sqrtf(s), 1e-12f);
        if (t < 128) rq[t] = r; else rk[t - 128] = r;
    }
    __syncthreads();

    const int wave = t >> 6, lane = t & 63, m16 = lane & 15, quad = lane >> 4;

    // --- matmul1: S = Q^T K  (wave owns j-tile = wave*16..+15, all 8 k-tiles) ---
    f32x4 acc[8] = {};
    for (int kk = 0; kk < 4; ++kk) {
        const int kb = kk * 32 + quad * 8;
        bf16x8 a = *(const bf16x8*)(&Qt[(wave * 16 + m16) * 136 + kb]);
#pragma unroll
        for (int nt = 0; nt < 8; ++nt) {
            bf16x8 bf = *(const bf16x8*)(&Kt[(nt * 16 + m16) * 136 + kb]);
            acc[nt] = MFMA16(a, bf, acc[nt]);
        }
    }
    const float tv = temp[head];
    float rqv[4];
#pragma unroll
    for (int r = 0; r < 4; ++r) rqv[r] = rq[wave * 16 + quad * 4 + r] * tv;
    __syncthreads();  // all Qt/Kt reads done -> safe to overwrite region with St
#pragma unroll
    for (int nt = 0; nt < 8; ++nt) {
        int kcol = nt * 16 + m16;
        float rkv = rk[kcol];
        f32x4 v = acc[nt], o;
        o[0] = v[0] * rqv[0] * rkv; o[1] = v[1] * rqv[1] * rkv;
        o[2] = v[2] * rqv[2] * rkv; o[3] = v[3] * rqv[3] * rkv;
        *(f32x4*)(&St[kcol * 132 + wave * 16 + quad * 4]) = o;
    }
    __syncthreads();

    // --- softmax over j, per column k.  4 threads per column. ---
    {
        const int col = t >> 2, part = t & 3;
        const float* Srow = &St[col * 132 + part * 32];
        float e[32];
#pragma unroll
        for (int c = 0; c < 8; ++c) {
            f32x4 v = *(const f32x4*)(&Srow[c * 4]);
            e[c * 4 + 0] = v[0]; e[c * 4 + 1] = v[1]; e[c * 4 + 2] = v[2]; e[c * 4 + 3] = v[3];
        }
        float lmax = -1e30f;
#pragma unroll
        for (int jj = 0; jj < 32; ++jj) lmax = fmaxf(lmax, e[jj]);
        lmax = fmaxf(lmax, __shfl_xor(lmax, 1));
        lmax = fmaxf(lmax, __shfl_xor(lmax, 2));
        float lsum = 0.f;
#pragma unroll
        for (int jj = 0; jj < 32; ++jj) { e[jj] = __expf(e[jj] - lmax); lsum += e[jj]; }
        lsum += __shfl_xor(lsum, 1);
        lsum += __shfl_xor(lsum, 2);
        float inv = 1.0f / lsum;
        u32* prow = (u32*)&Pt[col * 136 + part * 32];
#pragma unroll
        for (int c2 = 0; c2 < 16; ++c2) {
            u32 lo = f2bf(e[2 * c2] * inv), hi = f2bf(e[2 * c2 + 1] * inv);
            prow[c2] = lo | (hi << 16);
        }
    }
    __syncthreads();

    // --- matmul2: O = V * P  (wave owns i-tile = wave*16..+15) ---
    f32x4 acc2[8] = {};
    for (int kk = 0; kk < 4; ++kk) {
        const int kb = kk * 32 + quad * 8;
        bf16x8 a = *(const bf16x8*)(&Vs[(wave * 16 + m16) * 136 + kb]);
#pragma unroll
        for (int nt = 0; nt < 8; ++nt) {
            bf16x8 bf = *(const bf16x8*)(&Pt[(nt * 16 + m16) * 136 + kb]);
            acc2[nt] = MFMA16(a, bf, acc2[nt]);
        }
    }
#pragma unroll
    for (int nt = 0; nt < 8; ++nt) {
        int kcol = nt * 16 + m16;
#pragma unroll
        for (int r = 0; r < 4; ++r)
            Osh[(wave * 16 + quad * 4 + r) * 136 + kcol] = f2bf(acc2[nt][r]);
    }
    __syncthreads();

    u16* ob = outp + (((size_t)(b * 128 + ch)) << 14);
    for (int it = 0; it < 4; ++it) {
        int idx = it * 512 + t;
        int row = idx >> 4, cp = idx & 15;
        *(uint4*)(&ob[(row << 7) + cp * 8]) = *(const uint4*)(&Osh[row * 136 + cp * 8]);
    }
}

// ---------------------------------------------------------------------------
// K4: proj 1x1 conv.  out[b][co<128][h][w] (fp32) = sum_ci W[co][ci]*ain[b][ci][h][w] + b[co]
// ---------------------------------------------------------------------------
__global__ __launch_bounds__(512, 1) void k_proj(const u16* __restrict__ ain,
                                                 const float* __restrict__ w,
                                                 const float* __restrict__ bias,
                                                 float* __restrict__ outp) {
    extern __shared__ char smem[];
    u16* xT = (u16*)smem;               // [128 p][136 ci]
    float* Cs = (float*)(xT + 128 * 136);  // [128 co][132 p]
    const int h = blockIdx.x, b = blockIdx.y;
    const int t = threadIdx.x;

    const u16* ab = ain + (((size_t)(b * 128)) << 14) + (h << 7);
    for (int it = 0; it < 32; ++it) {
        int idx = it * 512 + t;
        int ci = idx >> 7, p = idx & 127;
        xT[p * 136 + ci] = ab[((size_t)ci << 14) + p];
    }
    __syncthreads();

    const int wave = t >> 6, lane = t & 63, m16 = lane & 15, quad = lane >> 4;
    f32x4 acc[8] = {};
    for (int kk = 0; kk < 4; ++kk) {
        const int kb = kk * 32 + quad * 8;
        const float* wp = w + (wave * 16 + m16) * 128 + kb;
        float4 w0 = *(const float4*)wp;
        float4 w1 = *(const float4*)(wp + 4);
        bf16x8 a;
        a[0] = (short)f2bf(w0.x); a[1] = (short)f2bf(w0.y);
        a[2] = (short)f2bf(w0.z); a[3] = (short)f2bf(w0.w);
        a[4] = (short)f2bf(w1.x); a[5] = (short)f2bf(w1.y);
        a[6] = (short)f2bf(w1.z); a[7] = (short)f2bf(w1.w);
#pragma unroll
        for (int nt = 0; nt < 8; ++nt) {
            bf16x8 bf = *(const bf16x8*)(&xT[(nt * 16 + m16) * 136 + kb]);
            acc[nt] = MFMA16(a, bf, acc[nt]);
        }
    }
    float bv[4];
#pragma unroll
    for (int r = 0; r < 4; ++r) bv[r] = bias[wave * 16 + quad * 4 + r];
#pragma unroll
    for (int nt = 0; nt < 8; ++nt) {
        int p = nt * 16 + m16;
#pragma unroll
        for (int r = 0; r < 4; ++r)
            Cs[(wave * 16 + quad * 4 + r) * 132 + p] = acc[nt][r] + bv[r];
    }
    __syncthreads();

    float* ob = outp + (((size_t)(b * 128)) << 14) + (h << 7);
    for (int it = 0; it < 8; ++it) {
        int idx = it * 512 + t;
        int row = idx >> 5, cp = idx & 31;
        *(float4*)(&ob[((size_t)row << 14) + cp * 4]) = *(const float4*)(&Cs[row * 132 + cp * 4]);
    }
}

// ---------------------------------------------------------------------------
extern "C" void kernel_launch(void* const* d_in, const int* in_sizes, int n_in,
                              void* d_out, int out_size, void* d_ws, size_t ws_size,
                              hipStream_t stream) {
    const float* x      = (const float*)d_in[0];
    const float* qkv_w  = (const float*)d_in[1];
    const float* qkv_b  = (const float*)d_in[2];
    const float* dw_w   = (const float*)d_in[3];
    const float* dw_b   = (const float*)d_in[4];
    const float* proj_w = (const float*)d_in[5];
    const float* proj_b = (const float*)d_in[6];
    const float* temp   = (const float*)d_in[7];
    float* out = (float*)d_out;

    // ws layout: buf1 [8*384*16384] bf16 (conv-out, later reused for attn-out)
    //            buf2 [8*384*16384] bf16 (qkv post-dw)   -> 192 MB total
    u16* buf1 = (u16*)d_ws;
    u16* buf2 = buf1 + (size_t)8 * 384 * 16384;

    hipFuncSetAttribute((const void*)k_qkv,  hipFuncAttributeMaxDynamicSharedMemorySize, 139264);
    hipFuncSetAttribute((const void*)k_attn, hipFuncAttributeMaxDynamicSharedMemorySize, 140288);
    hipFuncSetAttribute((const void*)k_proj, hipFuncAttributeMaxDynamicSharedMemorySize, 102400);

    k_qkv<<<dim3(128, 8), 512, 139264, stream>>>(x, qkv_w, qkv_b, buf1);
    k_dw<<<dim3(4, 384, 8), 256, 0, stream>>>(buf1, dw_w, dw_b, buf2);
    k_attn<<<dim3(128, 8), 512, 140288, stream>>>(buf2, temp, buf1);
    k_proj<<<dim3(128, 8), 512, 102400, stream>>>(buf1, proj_w, proj_b, out);
}

// Round 3
// 270.976 us; speedup vs baseline: 1.8015x; 1.0315x over previous
//
#include <hip/hip_runtime.h>

typedef unsigned short u16;
typedef unsigned int   u32;

typedef short bf16x8 __attribute__((ext_vector_type(8)));
typedef float f32x4  __attribute__((ext_vector_type(4)));

__device__ __forceinline__ float bf2f(u16 u) { return __uint_as_float(((u32)u) << 16); }
__device__ __forceinline__ u16 f2bf(float f) {
    u32 u = __float_as_uint(f);
    return (u16)((u + 0x7fffu + ((u >> 16) & 1u)) >> 16);
}

#define MFMA16(a, b, c) __builtin_amdgcn_mfma_f32_16x16x32_bf16(a, b, c, 0, 0, 0)

// ---------------------------------------------------------------------------
// K0: transpose x[b][ci][p] fp32 -> xT[b][p][ci] bf16.  One block per
// (128-px tile, b).  LDS tile with 4-elem XOR swizzle: element (ci,p) lives
// at ci*128 + ((p>>2) ^ (ci>>3))*4 + (p&3)  -> conflict-free writes & reads.
// ---------------------------------------------------------------------------
__global__ __launch_bounds__(256, 4) void k_xpose(const float* __restrict__ x,
                                                  u16* __restrict__ xT) {
    __shared__ u16 Xs[128 * 128];
    const int ptile = blockIdx.x, b = blockIdx.y;
    const int t = threadIdx.x;
    const float* xb = x + (((size_t)b) << 21) + ptile * 128;
#pragma unroll
    for (int i = 0; i < 16; ++i) {
        int idx = i * 256 + t;
        int ci = idx >> 5, pq = idx & 31;
        float4 v = *(const float4*)(xb + (((size_t)ci) << 14) + pq * 4);
        u32 lo = (u32)f2bf(v.x) | ((u32)f2bf(v.y) << 16);
        u32 hi = (u32)f2bf(v.z) | ((u32)f2bf(v.w) << 16);
        uint2 pk; pk.x = lo; pk.y = hi;
        int cq = ci >> 3;
        *(uint2*)(&Xs[ci * 128 + ((pq ^ cq) << 2)]) = pk;
    }
    __syncthreads();
    u16* ob = xT + (((size_t)b) << 21) + ((size_t)(ptile * 128)) * 128;
#pragma unroll
    for (int j = 0; j < 8; ++j) {
        int p = j * 16 + (t >> 4), cq = t & 15;
        u16 tmp[8];
#pragma unroll
        for (int c = 0; c < 8; ++c) {
            int ci = cq * 8 + c;
            tmp[c] = Xs[ci * 128 + (((p >> 2) ^ cq) << 2) + (p & 3)];
        }
        *(uint4*)(&ob[(size_t)p * 128 + cq * 8]) = *(const uint4*)tmp;
    }
}

// ---------------------------------------------------------------------------
// K1: qkv 1x1 conv from xT.  out1[b][co][h][w] bf16 = sum_ci W[co][ci]*x + b.
// Block = (h row, co-group of 128, b).  B-tile (128 px x 128 ci bf16, 32 KB)
// staged with 16B-group XOR swizzle (g ^ (p&15)): uint4 writes and b128
// fragment reads both conflict-free.  A (W) loaded fp32->bf16 to regs.
// LDS 66 KB dynamic -> 2 blocks/CU.
// ---------------------------------------------------------------------------
__global__ __launch_bounds__(512, 2) void k_qkv(const u16* __restrict__ xT,
                                                const float* __restrict__ w,
                                                const float* __restrict__ bias,
                                                u16* __restrict__ out1) {
    extern __shared__ char smem[];
    u16* Bt = (u16*)smem;            // 2048 slots x 16B = 32 KB, swizzled [p][g]
    u16* Cs = Bt + 2048 * 8;         // [128 co][136 p] = 34 KB
    const int h = blockIdx.x, cg = blockIdx.y, b = blockIdx.z;
    const int t = threadIdx.x;

    const u16* xb = xT + (((size_t)b) << 21) + ((size_t)(h * 128)) * 128;
#pragma unroll
    for (int i = 0; i < 4; ++i) {
        int slot = i * 512 + t;
        int p = slot >> 4, g = slot & 15;
        int gg = g ^ (p & 15);
        uint4 v = *(const uint4*)(&xb[p * 128 + gg * 8]);
        *(uint4*)(&Bt[slot * 8]) = v;
    }

    const int wave = t >> 6, lane = t & 63, m16 = lane & 15, quad = lane >> 4;
    // A fragments: W rows (co = cg*128 + wave*16 + m16), fp32 -> bf16
    bf16x8 afr[4];
    {
        const float* wp0 = w + (size_t)(cg * 128 + wave * 16 + m16) * 128 + quad * 8;
#pragma unroll
        for (int kk = 0; kk < 4; ++kk) {
            float4 w0 = *(const float4*)(wp0 + kk * 32);
            float4 w1 = *(const float4*)(wp0 + kk * 32 + 4);
            bf16x8 a;
            a[0] = (short)f2bf(w0.x); a[1] = (short)f2bf(w0.y);
            a[2] = (short)f2bf(w0.z); a[3] = (short)f2bf(w0.w);
            a[4] = (short)f2bf(w1.x); a[5] = (short)f2bf(w1.y);
            a[6] = (short)f2bf(w1.z); a[7] = (short)f2bf(w1.w);
            afr[kk] = a;
        }
    }
    __syncthreads();

    f32x4 acc[8] = {};
#pragma unroll
    for (int kk = 0; kk < 4; ++kk) {
        const int g = kk * 4 + quad;
#pragma unroll
        for (int nt = 0; nt < 8; ++nt) {
            int p = nt * 16 + m16;
            bf16x8 bf = *(const bf16x8*)(&Bt[p * 128 + ((g ^ (p & 15)) << 3)]);
            acc[nt] = MFMA16(afr[kk], bf, acc[nt]);
        }
    }

    float bv[4];
#pragma unroll
    for (int r = 0; r < 4; ++r) bv[r] = bias[cg * 128 + wave * 16 + quad * 4 + r];
#pragma unroll
    for (int nt = 0; nt < 8; ++nt) {
        int p = nt * 16 + m16;
#pragma unroll
        for (int r = 0; r < 4; ++r)
            Cs[(wave * 16 + quad * 4 + r) * 136 + p] = f2bf(acc[nt][r] + bv[r]);
    }
    __syncthreads();

    u16* ob = out1 + (((size_t)(b * 384 + cg * 128)) << 14) + (h << 7);
#pragma unroll
    for (int it = 0; it < 4; ++it) {
        int idx = it * 512 + t;
        int co = idx >> 4, cp = idx & 15;
        *(uint4*)(&ob[((size_t)co << 14) + cp * 8]) = *(const uint4*)(&Cs[co * 136 + cp * 8]);
    }
}

// ---------------------------------------------------------------------------
// K2: depthwise 3x3, zero pad, + bias.  in/out bf16 [8][384][128][128]
// LDS-tiled: block = (htile of 32 rows, ch, b).
// ---------------------------------------------------------------------------
__global__ __launch_bounds__(256, 4) void k_dw(const u16* __restrict__ in,
                                               const float* __restrict__ w,
                                               const float* __restrict__ bias,
                                               u16* __restrict__ out) {
    __shared__ u16 tile[34 * 144];
    const int htile = blockIdx.x;   // 0..3 -> rows htile*32 .. +31
    const int ch = blockIdx.y;      // 0..383
    const int b = blockIdx.z;       // 0..7
    const int t = threadIdx.x;
    const u16* base = in + (((size_t)(b * 384 + ch)) << 14);

    if (t < 68) {
        int r = t >> 1, side = t & 1;
        uint4 z = {0, 0, 0, 0};
        *(uint4*)(&tile[r * 144 + side * 136]) = z;
    }
    for (int it = 0; it < 3; ++it) {
        int idx = it * 256 + t;
        if (idx < 544) {
            int r = idx >> 4, cq = idx & 15;
            int y = htile * 32 - 1 + r;
            uint4 v = {0, 0, 0, 0};
            if (y >= 0 && y <= 127) v = *(const uint4*)(base + (y << 7) + cq * 8);
            *(uint4*)(&tile[r * 144 + 8 + cq * 8]) = v;
        }
    }
    float wg[9];
#pragma unroll
    for (int i = 0; i < 9; ++i) wg[i] = w[ch * 9 + i];
    const float bv = bias[ch];
    __syncthreads();

    const int r = t >> 4, cp = t & 15, c0 = cp * 8;
    u16* ob = out + (((size_t)(b * 384 + ch)) << 14) + ((htile * 32) << 7) + c0;
#pragma unroll
    for (int half = 0; half < 2; ++half) {
        const int ro = r + half * 16;
        float acc[8];
#pragma unroll
        for (int c = 0; c < 8; ++c) acc[c] = bv;
#pragma unroll
        for (int dy = 0; dy < 3; ++dy) {
            const u16* row = &tile[(ro + dy) * 144 + 8 + c0];
            float v[10];
            v[0] = bf2f(row[-1]);
            uint4 m = *(const uint4*)row;
            v[1] = bf2f((u16)(m.x & 0xffff)); v[2] = bf2f((u16)(m.x >> 16));
            v[3] = bf2f((u16)(m.y & 0xffff)); v[4] = bf2f((u16)(m.y >> 16));
            v[5] = bf2f((u16)(m.z & 0xffff)); v[6] = bf2f((u16)(m.z >> 16));
            v[7] = bf2f((u16)(m.w & 0xffff)); v[8] = bf2f((u16)(m.w >> 16));
            v[9] = bf2f(row[8]);
#pragma unroll
            for (int dx = 0; dx < 3; ++dx) {
                const float wv = wg[dy * 3 + dx];
#pragma unroll
                for (int c = 0; c < 8; ++c) acc[c] += wv * v[c + dx];
            }
        }
        u32 pk[4];
#pragma unroll
        for (int c2 = 0; c2 < 4; ++c2) {
            u32 lo = f2bf(acc[2 * c2]), hi = f2bf(acc[2 * c2 + 1]);
            pk[c2] = lo | (hi << 16);
        }
        *(uint4*)(ob + (ro << 7)) = *(uint4*)pk;
    }
}

// ---------------------------------------------------------------------------
// K3: per-(b,head,c) attention. One block per (ch, b), 512 threads / 8 waves.
// ---------------------------------------------------------------------------
__global__ __launch_bounds__(512, 1) void k_attn(const u16* __restrict__ qkv,
                                                 const float* __restrict__ temp,
                                                 u16* __restrict__ outp) {
    extern __shared__ char smem[];
    u16* Qt = (u16*)smem;           // [128 j][136 i]
    u16* Kt = Qt + 128 * 136;       // [128 k][136 i]
    u16* Vs = Kt + 128 * 136;       // [128 i][136 j]
    u16* Pt = Vs + 128 * 136;       // [128 k][136 j]
    float* rq = (float*)(Pt + 128 * 136);  // [128]
    float* rk = rq + 128;                  // [128]
    float* St = (float*)smem;       // [128 k][132 j]  (aliases Qt/Kt)
    u16* Osh = (u16*)smem;          // [128 i][136 k]  (aliases)

    const int ch = blockIdx.x, b = blockIdx.y;
    const int head = ch >> 5;
    const int t = threadIdx.x;
    const size_t qoff = ((size_t)(b * 384 + ch)) << 14;
    const size_t koff = ((size_t)(b * 384 + 128 + ch)) << 14;
    const size_t voff = ((size_t)(b * 384 + 256 + ch)) << 14;

    for (int it = 0; it < 4; ++it) {
        int idx = it * 512 + t;
        int row = idx >> 4, cp = idx & 15;
        *(uint4*)(&Vs[row * 136 + cp * 8]) = *(const uint4*)(&qkv[voff + (row << 7) + cp * 8]);
    }
    for (int it = 0; it < 32; ++it) {
        int idx = it * 512 + t;
        int i = idx >> 7, j = idx & 127;
        Qt[j * 136 + i] = qkv[qoff + (i << 7) + j];
        Kt[j * 136 + i] = qkv[koff + (i << 7) + j];
    }
    __syncthreads();

    if (t < 256) {
        const u16* rowp = (t < 128) ? &Qt[t * 136] : &Kt[(t - 128) * 136];
        float s = 0.f;
#pragma unroll
        for (int c = 0; c < 16; ++c) {
            uint4 v = *(const uint4*)(rowp + c * 8);
            float f0 = bf2f((u16)(v.x & 0xffff)), f1 = bf2f((u16)(v.x >> 16));
            float f2 = bf2f((u16)(v.y & 0xffff)), f3 = bf2f((u16)(v.y >> 16));
            float f4 = bf2f((u16)(v.z & 0xffff)), f5 = bf2f((u16)(v.z >> 16));
            float f6 = bf2f((u16)(v.w & 0xffff)), f7 = bf2f((u16)(v.w >> 16));
            s += f0 * f0 + f1 * f1 + f2 * f2 + f3 * f3 + f4 * f4 + f5 * f5 + f6 * f6 + f7 * f7;
        }
        float r = 1.0f / fmaxf(sqrtf(s), 1e-12f);
        if (t < 128) rq[t] = r; else rk[t - 128] = r;
    }
    __syncthreads();

    const int wave = t >> 6, lane = t & 63, m16 = lane & 15, quad = lane >> 4;

    f32x4 acc[8] = {};
    for (int kk = 0; kk < 4; ++kk) {
        const int kb = kk * 32 + quad * 8;
        bf16x8 a = *(const bf16x8*)(&Qt[(wave * 16 + m16) * 136 + kb]);
#pragma unroll
        for (int nt = 0; nt < 8; ++nt) {
            bf16x8 bf = *(const bf16x8*)(&Kt[(nt * 16 + m16) * 136 + kb]);
            acc[nt] = MFMA16(a, bf, acc[nt]);
        }
    }
    const float tv = temp[head];
    float rqv[4];
#pragma unroll
    for (int r = 0; r < 4; ++r) rqv[r] = rq[wave * 16 + quad * 4 + r] * tv;
    __syncthreads();
#pragma unroll
    for (int nt = 0; nt < 8; ++nt) {
        int kcol = nt * 16 + m16;
        float rkv = rk[kcol];
        f32x4 v = acc[nt], o;
        o[0] = v[0] * rqv[0] * rkv; o[1] = v[1] * rqv[1] * rkv;
        o[2] = v[2] * rqv[2] * rkv; o[3] = v[3] * rqv[3] * rkv;
        *(f32x4*)(&St[kcol * 132 + wave * 16 + quad * 4]) = o;
    }
    __syncthreads();

    {
        const int col = t >> 2, part = t & 3;
        const float* Srow = &St[col * 132 + part * 32];
        float e[32];
#pragma unroll
        for (int c = 0; c < 8; ++c) {
            f32x4 v = *(const f32x4*)(&Srow[c * 4]);
            e[c * 4 + 0] = v[0]; e[c * 4 + 1] = v[1]; e[c * 4 + 2] = v[2]; e[c * 4 + 3] = v[3];
        }
        float lmax = -1e30f;
#pragma unroll
        for (int jj = 0; jj < 32; ++jj) lmax = fmaxf(lmax, e[jj]);
        lmax = fmaxf(lmax, __shfl_xor(lmax, 1));
        lmax = fmaxf(lmax, __shfl_xor(lmax, 2));
        float lsum = 0.f;
#pragma unroll
        for (int jj = 0; jj < 32; ++jj) { e[jj] = __expf(e[jj] - lmax); lsum += e[jj]; }
        lsum += __shfl_xor(lsum, 1);
        lsum += __shfl_xor(lsum, 2);
        float inv = 1.0f / lsum;
        u32* prow = (u32*)&Pt[col * 136 + part * 32];
#pragma unroll
        for (int c2 = 0; c2 < 16; ++c2) {
            u32 lo = f2bf(e[2 * c2] * inv), hi = f2bf(e[2 * c2 + 1] * inv);
            prow[c2] = lo | (hi << 16);
        }
    }
    __syncthreads();

    f32x4 acc2[8] = {};
    for (int kk = 0; kk < 4; ++kk) {
        const int kb = kk * 32 + quad * 8;
        bf16x8 a = *(const bf16x8*)(&Vs[(wave * 16 + m16) * 136 + kb]);
#pragma unroll
        for (int nt = 0; nt < 8; ++nt) {
            bf16x8 bf = *(const bf16x8*)(&Pt[(nt * 16 + m16) * 136 + kb]);
            acc2[nt] = MFMA16(a, bf, acc2[nt]);
        }
    }
#pragma unroll
    for (int nt = 0; nt < 8; ++nt) {
        int kcol = nt * 16 + m16;
#pragma unroll
        for (int r = 0; r < 4; ++r)
            Osh[(wave * 16 + quad * 4 + r) * 136 + kcol] = f2bf(acc2[nt][r]);
    }
    __syncthreads();

    u16* ob = outp + (((size_t)(b * 128 + ch)) << 14);
    for (int it = 0; it < 4; ++it) {
        int idx = it * 512 + t;
        int row = idx >> 4, cp = idx & 15;
        *(uint4*)(&ob[(row << 7) + cp * 8]) = *(const uint4*)(&Osh[row * 136 + cp * 8]);
    }
}

// ---------------------------------------------------------------------------
// K4: proj 1x1 conv.  out[b][co<128][h][w] fp32.
// ---------------------------------------------------------------------------
__global__ __launch_bounds__(512, 1) void k_proj(const u16* __restrict__ ain,
                                                 const float* __restrict__ w,
                                                 const float* __restrict__ bias,
                                                 float* __restrict__ outp) {
    extern __shared__ char smem[];
    u16* xT = (u16*)smem;               // [128 p][136 ci]
    float* Cs = (float*)(xT + 128 * 136);  // [128 co][132 p]
    const int h = blockIdx.x, b = blockIdx.y;
    const int t = threadIdx.x;

    const u16* ab = ain + (((size_t)(b * 128)) << 14) + (h << 7);
    for (int it = 0; it < 32; ++it) {
        int idx = it * 512 + t;
        int ci = idx >> 7, p = idx & 127;
        xT[p * 136 + ci] = ab[((size_t)ci << 14) + p];
    }
    __syncthreads();

    const int wave = t >> 6, lane = t & 63, m16 = lane & 15, quad = lane >> 4;
    f32x4 acc[8] = {};
    for (int kk = 0; kk < 4; ++kk) {
        const int kb = kk * 32 + quad * 8;
        const float* wp = w + (wave * 16 + m16) * 128 + kb;
        float4 w0 = *(const float4*)wp;
        float4 w1 = *(const float4*)(wp + 4);
        bf16x8 a;
        a[0] = (short)f2bf(w0.x); a[1] = (short)f2bf(w0.y);
        a[2] = (short)f2bf(w0.z); a[3] = (short)f2bf(w0.w);
        a[4] = (short)f2bf(w1.x); a[5] = (short)f2bf(w1.y);
        a[6] = (short)f2bf(w1.z); a[7] = (short)f2bf(w1.w);
#pragma unroll
        for (int nt = 0; nt < 8; ++nt) {
            bf16x8 bf = *(const bf16x8*)(&xT[(nt * 16 + m16) * 136 + kb]);
            acc[nt] = MFMA16(a, bf, acc[nt]);
        }
    }
    float bv[4];
#pragma unroll
    for (int r = 0; r < 4; ++r) bv[r] = bias[wave * 16 + quad * 4 + r];
#pragma unroll
    for (int nt = 0; nt < 8; ++nt) {
        int p = nt * 16 + m16;
#pragma unroll
        for (int r = 0; r < 4; ++r)
            Cs[(wave * 16 + quad * 4 + r) * 132 + p] = acc[nt][r] + bv[r];
    }
    __syncthreads();

    float* ob = outp + (((size_t)(b * 128)) << 14) + (h << 7);
    for (int it = 0; it < 8; ++it) {
        int idx = it * 512 + t;
        int row = idx >> 5, cp = idx & 31;
        *(float4*)(&ob[((size_t)row << 14) + cp * 4]) = *(const float4*)(&Cs[row * 132 + cp * 4]);
    }
}

// ---------------------------------------------------------------------------
extern "C" void kernel_launch(void* const* d_in, const int* in_sizes, int n_in,
                              void* d_out, int out_size, void* d_ws, size_t ws_size,
                              hipStream_t stream) {
    const float* x      = (const float*)d_in[0];
    const float* qkv_w  = (const float*)d_in[1];
    const float* qkv_b  = (const float*)d_in[2];
    const float* dw_w   = (const float*)d_in[3];
    const float* dw_b   = (const float*)d_in[4];
    const float* proj_w = (const float*)d_in[5];
    const float* proj_b = (const float*)d_in[6];
    const float* temp   = (const float*)d_in[7];
    float* out = (float*)d_out;

    // ws layout: buf1 [8*384*16384] bf16 (conv-out, later attn-out)
    //            buf2 [8*384*16384] bf16 (xT first 32 MB, then qkv post-dw)
    u16* buf1 = (u16*)d_ws;
    u16* buf2 = buf1 + (size_t)8 * 384 * 16384;

    hipFuncSetAttribute((const void*)k_qkv,  hipFuncAttributeMaxDynamicSharedMemorySize, 67584);
    hipFuncSetAttribute((const void*)k_attn, hipFuncAttributeMaxDynamicSharedMemorySize, 140288);
    hipFuncSetAttribute((const void*)k_proj, hipFuncAttributeMaxDynamicSharedMemorySize, 102400);

    // xT aliases buf2 (32 MB) — dead before k_dw overwrites buf2.
    k_xpose<<<dim3(128, 8), 256, 0, stream>>>(x, buf2);
    k_qkv<<<dim3(128, 3, 8), 512, 67584, stream>>>(buf2, qkv_w, qkv_b, buf1);
    k_dw<<<dim3(4, 384, 8), 256, 0, stream>>>(buf1, dw_w, dw_b, buf2);
    k_attn<<<dim3(128, 8), 512, 140288, stream>>>(buf2, temp, buf1);
    k_proj<<<dim3(128, 8), 512, 102400, stream>>>(buf1, proj_w, proj_b, out);
}

// Round 5
// 258.894 us; speedup vs baseline: 1.8856x; 1.0467x over previous
//
#include <hip/hip_runtime.h>

typedef unsigned short u16;
typedef unsigned int   u32;

typedef short bf16x8 __attribute__((ext_vector_type(8)));
typedef float f32x4  __attribute__((ext_vector_type(4)));

__device__ __forceinline__ float bf2f(u16 u) { return __uint_as_float(((u32)u) << 16); }
__device__ __forceinline__ u16 f2bf(float f) {
    u32 u = __float_as_uint(f);
    return (u16)((u + 0x7fffu + ((u >> 16) & 1u)) >> 16);
}

#define MFMA16(a, b, c) __builtin_amdgcn_mfma_f32_16x16x32_bf16(a, b, c, 0, 0, 0)

// ---------------------------------------------------------------------------
// K0: transpose x[b][ci][p] fp32 -> xT[b][p][ci] bf16.
// ---------------------------------------------------------------------------
__global__ __launch_bounds__(256, 4) void k_xpose(const float* __restrict__ x,
                                                  u16* __restrict__ xT) {
    __shared__ u16 Xs[128 * 128];
    const int ptile = blockIdx.x, b = blockIdx.y;
    const int t = threadIdx.x;
    const float* xb = x + (((size_t)b) << 21) + ptile * 128;
#pragma unroll
    for (int i = 0; i < 16; ++i) {
        int idx = i * 256 + t;
        int ci = idx >> 5, pq = idx & 31;
        float4 v = *(const float4*)(xb + (((size_t)ci) << 14) + pq * 4);
        u32 lo = (u32)f2bf(v.x) | ((u32)f2bf(v.y) << 16);
        u32 hi = (u32)f2bf(v.z) | ((u32)f2bf(v.w) << 16);
        uint2 pk; pk.x = lo; pk.y = hi;
        int cq = ci >> 3;
        *(uint2*)(&Xs[ci * 128 + ((pq ^ cq) << 2)]) = pk;
    }
    __syncthreads();
    u16* ob = xT + (((size_t)b) << 21) + ((size_t)(ptile * 128)) * 128;
#pragma unroll
    for (int j = 0; j < 8; ++j) {
        int p = j * 16 + (t >> 4), cq = t & 15;
        u16 tmp[8];
#pragma unroll
        for (int c = 0; c < 8; ++c) {
            int ci = cq * 8 + c;
            tmp[c] = Xs[ci * 128 + (((p >> 2) ^ cq) << 2) + (p & 3)];
        }
        *(uint4*)(&ob[(size_t)p * 128 + cq * 8]) = *(const uint4*)tmp;
    }
}

// ---------------------------------------------------------------------------
// K1: qkv 1x1 conv from xT (swizzled B-tile, MFMA GEMM).
// ---------------------------------------------------------------------------
__global__ __launch_bounds__(512, 2) void k_qkv(const u16* __restrict__ xT,
                                                const float* __restrict__ w,
                                                const float* __restrict__ bias,
                                                u16* __restrict__ out1) {
    extern __shared__ char smem[];
    u16* Bt = (u16*)smem;            // 32 KB swizzled [p][g]
    u16* Cs = Bt + 2048 * 8;         // [128 co][136 p]
    const int h = blockIdx.x, cg = blockIdx.y, b = blockIdx.z;
    const int t = threadIdx.x;

    const u16* xb = xT + (((size_t)b) << 21) + ((size_t)(h * 128)) * 128;
#pragma unroll
    for (int i = 0; i < 4; ++i) {
        int slot = i * 512 + t;
        int p = slot >> 4, g = slot & 15;
        int gg = g ^ (p & 15);
        uint4 v = *(const uint4*)(&xb[p * 128 + gg * 8]);
        *(uint4*)(&Bt[slot * 8]) = v;
    }

    const int wave = t >> 6, lane = t & 63, m16 = lane & 15, quad = lane >> 4;
    bf16x8 afr[4];
    {
        const float* wp0 = w + (size_t)(cg * 128 + wave * 16 + m16) * 128 + quad * 8;
#pragma unroll
        for (int kk = 0; kk < 4; ++kk) {
            float4 w0 = *(const float4*)(wp0 + kk * 32);
            float4 w1 = *(const float4*)(wp0 + kk * 32 + 4);
            bf16x8 a;
            a[0] = (short)f2bf(w0.x); a[1] = (short)f2bf(w0.y);
            a[2] = (short)f2bf(w0.z); a[3] = (short)f2bf(w0.w);
            a[4] = (short)f2bf(w1.x); a[5] = (short)f2bf(w1.y);
            a[6] = (short)f2bf(w1.z); a[7] = (short)f2bf(w1.w);
            afr[kk] = a;
        }
    }
    __syncthreads();

    f32x4 acc[8] = {};
#pragma unroll
    for (int kk = 0; kk < 4; ++kk) {
        const int g = kk * 4 + quad;
#pragma unroll
        for (int nt = 0; nt < 8; ++nt) {
            int p = nt * 16 + m16;
            bf16x8 bf = *(const bf16x8*)(&Bt[p * 128 + ((g ^ (p & 15)) << 3)]);
            acc[nt] = MFMA16(afr[kk], bf, acc[nt]);
        }
    }

    float bv[4];
#pragma unroll
    for (int r = 0; r < 4; ++r) bv[r] = bias[cg * 128 + wave * 16 + quad * 4 + r];
#pragma unroll
    for (int nt = 0; nt < 8; ++nt) {
        int p = nt * 16 + m16;
#pragma unroll
        for (int r = 0; r < 4; ++r)
            Cs[(wave * 16 + quad * 4 + r) * 136 + p] = f2bf(acc[nt][r] + bv[r]);
    }
    __syncthreads();

    u16* ob = out1 + (((size_t)(b * 384 + cg * 128)) << 14) + (h << 7);
#pragma unroll
    for (int it = 0; it < 4; ++it) {
        int idx = it * 512 + t;
        int co = idx >> 4, cp = idx & 15;
        *(uint4*)(&ob[((size_t)co << 14) + cp * 8]) = *(const uint4*)(&Cs[co * 136 + cp * 8]);
    }
}

// ---------------------------------------------------------------------------
// K2: depthwise 3x3 (LDS-tiled).
// ---------------------------------------------------------------------------
__global__ __launch_bounds__(256, 4) void k_dw(const u16* __restrict__ in,
                                               const float* __restrict__ w,
                                               const float* __restrict__ bias,
                                               u16* __restrict__ out) {
    __shared__ u16 tile[34 * 144];
    const int htile = blockIdx.x;
    const int ch = blockIdx.y;
    const int b = blockIdx.z;
    const int t = threadIdx.x;
    const u16* base = in + (((size_t)(b * 384 + ch)) << 14);

    if (t < 68) {
        int r = t >> 1, side = t & 1;
        uint4 z = {0, 0, 0, 0};
        *(uint4*)(&tile[r * 144 + side * 136]) = z;
    }
    for (int it = 0; it < 3; ++it) {
        int idx = it * 256 + t;
        if (idx < 544) {
            int r = idx >> 4, cq = idx & 15;
            int y = htile * 32 - 1 + r;
            uint4 v = {0, 0, 0, 0};
            if (y >= 0 && y <= 127) v = *(const uint4*)(base + (y << 7) + cq * 8);
            *(uint4*)(&tile[r * 144 + 8 + cq * 8]) = v;
        }
    }
    float wg[9];
#pragma unroll
    for (int i = 0; i < 9; ++i) wg[i] = w[ch * 9 + i];
    const float bv = bias[ch];
    __syncthreads();

    const int r = t >> 4, cp = t & 15, c0 = cp * 8;
    u16* ob = out + (((size_t)(b * 384 + ch)) << 14) + ((htile * 32) << 7) + c0;
#pragma unroll
    for (int half = 0; half < 2; ++half) {
        const int ro = r + half * 16;
        float acc[8];
#pragma unroll
        for (int c = 0; c < 8; ++c) acc[c] = bv;
#pragma unroll
        for (int dy = 0; dy < 3; ++dy) {
            const u16* row = &tile[(ro + dy) * 144 + 8 + c0];
            float v[10];
            v[0] = bf2f(row[-1]);
            uint4 m = *(const uint4*)row;
            v[1] = bf2f((u16)(m.x & 0xffff)); v[2] = bf2f((u16)(m.x >> 16));
            v[3] = bf2f((u16)(m.y & 0xffff)); v[4] = bf2f((u16)(m.y >> 16));
            v[5] = bf2f((u16)(m.z & 0xffff)); v[6] = bf2f((u16)(m.z >> 16));
            v[7] = bf2f((u16)(m.w & 0xffff)); v[8] = bf2f((u16)(m.w >> 16));
            v[9] = bf2f(row[8]);
#pragma unroll
            for (int dx = 0; dx < 3; ++dx) {
                const float wv = wg[dy * 3 + dx];
#pragma unroll
                for (int c = 0; c < 8; ++c) acc[c] += wv * v[c + dx];
            }
        }
        u32 pk[4];
#pragma unroll
        for (int c2 = 0; c2 < 4; ++c2) {
            u32 lo = f2bf(acc[2 * c2]), hi = f2bf(acc[2 * c2 + 1]);
            pk[c2] = lo | (hi << 16);
        }
        *(uint4*)(ob + (ro << 7)) = *(uint4*)pk;
    }
}

// ---------------------------------------------------------------------------
// K3 v2: per-(b,ch) attention.  512 thr / 8 waves, 76 KB LDS -> 2 blocks/CU.
// Swizzled layout (16B groups): row r, group g stored at slot (g ^ (r&15)).
// mm1: wave owns k-strip; in-register softmax (shfl over quads).
// mm2: V A-frags prefetched direct from global; B from Pt (Qt alias).
// ---------------------------------------------------------------------------
__global__ __launch_bounds__(512, 4) void k_attn(const u16* __restrict__ qkv,
                                                 const float* __restrict__ temp,
                                                 u16* __restrict__ outp) {
    extern __shared__ char smem[];
    u16* Qt = (u16*)smem;            // [j][i] swizzled; Pt aliases
    u16* Kt = Qt + 16384;            // [k][i] swizzled; Osh aliases
    u16* Sg = Qt + 32768;            // [32][144] staging
    float* ps = (float*)(smem + 74752);   // [4][128]
    float* rq = (float*)(smem + 76800);   // [128]
    float* rk = (float*)(smem + 77312);   // [128]
    u16* Pt = Qt;                    // [k][j] swizzled (after mm1)
    u16* Osh = Kt;                   // [i][k] swizzled (after mm1)

    const int ch = blockIdx.x, b = blockIdx.y;
    const int head = ch >> 5;
    const int t = threadIdx.x;
    const size_t qoff = ((size_t)(b * 384 + ch)) << 14;
    const size_t koff = ((size_t)(b * 384 + 128 + ch)) << 14;
    const size_t voff = ((size_t)(b * 384 + 256 + ch)) << 14;

    const int wave = t >> 6, lane = t & 63, m16 = lane & 15, quad = lane >> 4;

    // --- prefetch V A-fragments for mm2 ---
    bf16x8 vfr[4];
    {
        const u16* vrow = qkv + voff + (size_t)(wave * 16 + m16) * 128 + quad * 8;
#pragma unroll
        for (int kk = 0; kk < 4; ++kk)
            vfr[kk] = *(const bf16x8*)(vrow + kk * 32);
    }

    // --- transpose Q,K into Qt,Kt (8 panel phases), fused ssq accumulation ---
    const int ldr = t >> 4, ldj8 = t & 15;
    const size_t ldsrc = (ldr < 16 ? qoff + (size_t)ldr * 128
                                   : koff + (size_t)(ldr - 16) * 128) + ldj8 * 8;
    const int gmat = t >> 8, gig = (t >> 7) & 1, gj = t & 127;
    const u16* gcol = &Sg[(gmat * 16 + gig * 8) * 144 + gj];
    u16* gdstbase = (gmat ? Kt : Qt) + gj * 128;
    float ssq = 0.f;
#pragma unroll
    for (int p = 0; p < 8; ++p) {
        *(uint4*)(&Sg[ldr * 144 + ldj8 * 8]) = *(const uint4*)(&qkv[ldsrc + (size_t)p * 2048]);
        __syncthreads();
        u16 tmp[8];
#pragma unroll
        for (int c = 0; c < 8; ++c) {
            u16 v = gcol[c * 144];
            tmp[c] = v;
            float f = bf2f(v);
            ssq += f * f;
        }
        int g = p * 2 + gig;
        *(uint4*)(gdstbase + ((g ^ (gj & 15)) << 3)) = *(const uint4*)tmp;
        __syncthreads();
    }
    ps[(gmat * 2 + gig) * 128 + gj] = ssq;
    __syncthreads();
    if (t < 256) {
        int mat = t >> 7, j = t & 127;
        float s = ps[(mat * 2) * 128 + j] + ps[(mat * 2 + 1) * 128 + j];
        float r = 1.0f / fmaxf(sqrtf(s), 1e-12f);
        if (mat == 0) rq[j] = r; else rk[j] = r;
    }
    __syncthreads();

    // --- mm1: S[j,k] for wave's k-strip ---
    f32x4 S[8] = {};
#pragma unroll
    for (int kk = 0; kk < 4; ++kk) {
        const int sw = ((kk * 4 + quad) ^ m16) << 3;
        bf16x8 bf = *(const bf16x8*)(&Kt[(wave * 16 + m16) * 128 + sw]);
#pragma unroll
        for (int jt = 0; jt < 8; ++jt) {
            bf16x8 af = *(const bf16x8*)(&Qt[(jt * 16 + m16) * 128 + sw]);
            S[jt] = MFMA16(af, bf, S[jt]);
        }
    }

    // --- in-register softmax over j (column k = wave*16+m16) ---
    const float sc = temp[head] * rk[wave * 16 + m16];
    float vals[8][4];
    float vmax = -1e30f;
#pragma unroll
    for (int jt = 0; jt < 8; ++jt)
#pragma unroll
        for (int r = 0; r < 4; ++r) {
            float v = S[jt][r] * (rq[jt * 16 + quad * 4 + r] * sc);
            vals[jt][r] = v;
            vmax = fmaxf(vmax, v);
        }
    vmax = fmaxf(vmax, __shfl_xor(vmax, 16));
    vmax = fmaxf(vmax, __shfl_xor(vmax, 32));
    float sum = 0.f;
#pragma unroll
    for (int jt = 0; jt < 8; ++jt)
#pragma unroll
        for (int r = 0; r < 4; ++r) {
            float e = __expf(vals[jt][r] - vmax);
            vals[jt][r] = e;
            sum += e;
        }
    sum += __shfl_xor(sum, 16);
    sum += __shfl_xor(sum, 32);
    const float inv = 1.0f / sum;

    __syncthreads();   // all Qt reads done -> Pt (alias) writable

    // --- write P (bf16) to Pt[k][j] swizzled ---
    {
        const int k = wave * 16 + m16;
        u16* prow = Pt + k * 128;
#pragma unroll
        for (int jt = 0; jt < 8; ++jt)
#pragma unroll
            for (int pr = 0; pr < 2; ++pr) {
                int j0 = jt * 16 + quad * 4 + pr * 2;
                u32 pk = (u32)f2bf(vals[jt][pr * 2] * inv) |
                         ((u32)f2bf(vals[jt][pr * 2 + 1] * inv) << 16);
                *(u32*)(prow + (((j0 >> 3) ^ (k & 15)) << 3) + (j0 & 7)) = pk;
            }
    }
    __syncthreads();

    // --- mm2: O[i,k] = sum_j V[i,j] P[j,k] ---
    f32x4 O[8] = {};
#pragma unroll
    for (int kk = 0; kk < 4; ++kk) {
        const int sw = ((kk * 4 + quad) ^ m16) << 3;
#pragma unroll
        for (int nt = 0; nt < 8; ++nt) {
            bf16x8 bf = *(const bf16x8*)(&Pt[(nt * 16 + m16) * 128 + sw]);
            O[nt] = MFMA16(vfr[kk], bf, O[nt]);
        }
    }

    // --- stage O to Osh (Kt alias), swizzled [i][k] ---
#pragma unroll
    for (int nt = 0; nt < 8; ++nt) {
        int k = nt * 16 + m16;
#pragma unroll
        for (int r = 0; r < 4; ++r) {
            int i = wave * 16 + quad * 4 + r;
            Osh[i * 128 + (((k >> 3) ^ (i & 15)) << 3) + (k & 7)] = f2bf(O[nt][r]);
        }
    }
    __syncthreads();

    // --- coalesced store-out ---
    u16* ob = outp + (((size_t)(b * 128 + ch)) << 14);
#pragma unroll
    for (int it = 0; it < 4; ++it) {
        int idx = it * 512 + t;
        int row = idx >> 4, gk = idx & 15;
        uint4 v = *(const uint4*)(&Osh[row * 128 + ((gk ^ (row & 15)) << 3)]);
        *(uint4*)(&ob[(row << 7) + gk * 8]) = v;
    }
}

// ---------------------------------------------------------------------------
// K4: proj 1x1 conv.  out[b][co<128][h][w] fp32.
// ---------------------------------------------------------------------------
__global__ __launch_bounds__(512, 1) void k_proj(const u16* __restrict__ ain,
                                                 const float* __restrict__ w,
                                                 const float* __restrict__ bias,
                                                 float* __restrict__ outp) {
    extern __shared__ char smem[];
    u16* xT = (u16*)smem;               // [128 p][136 ci]
    float* Cs = (float*)(xT + 128 * 136);  // [128 co][132 p]
    const int h = blockIdx.x, b = blockIdx.y;
    const int t = threadIdx.x;

    const u16* ab = ain + (((size_t)(b * 128)) << 14) + (h << 7);
    for (int it = 0; it < 32; ++it) {
        int idx = it * 512 + t;
        int ci = idx >> 7, p = idx & 127;
        xT[p * 136 + ci] = ab[((size_t)ci << 14) + p];
    }
    __syncthreads();

    const int wave = t >> 6, lane = t & 63, m16 = lane & 15, quad = lane >> 4;
    f32x4 acc[8] = {};
    for (int kk = 0; kk < 4; ++kk) {
        const int kb = kk * 32 + quad * 8;
        const float* wp = w + (wave * 16 + m16) * 128 + kb;
        float4 w0 = *(const float4*)wp;
        float4 w1 = *(const float4*)(wp + 4);
        bf16x8 a;
        a[0] = (short)f2bf(w0.x); a[1] = (short)f2bf(w0.y);
        a[2] = (short)f2bf(w0.z); a[3] = (short)f2bf(w0.w);
        a[4] = (short)f2bf(w1.x); a[5] = (short)f2bf(w1.y);
        a[6] = (short)f2bf(w1.z); a[7] = (short)f2bf(w1.w);
#pragma unroll
        for (int nt = 0; nt < 8; ++nt) {
            bf16x8 bf = *(const bf16x8*)(&xT[(nt * 16 + m16) * 136 + kb]);
            acc[nt] = MFMA16(a, bf, acc[nt]);
        }
    }
    float bv[4];
#pragma unroll
    for (int r = 0; r < 4; ++r) bv[r] = bias[wave * 16 + quad * 4 + r];
#pragma unroll
    for (int nt = 0; nt < 8; ++nt) {
        int p = nt * 16 + m16;
#pragma unroll
        for (int r = 0; r < 4; ++r)
            Cs[(wave * 16 + quad * 4 + r) * 132 + p] = acc[nt][r] + bv[r];
    }
    __syncthreads();

    float* ob = outp + (((size_t)(b * 128)) << 14) + (h << 7);
    for (int it = 0; it < 8; ++it) {
        int idx = it * 512 + t;
        int row = idx >> 5, cp = idx & 31;
        *(float4*)(&ob[((size_t)row << 14) + cp * 4]) = *(const float4*)(&Cs[row * 132 + cp * 4]);
    }
}

// ---------------------------------------------------------------------------
extern "C" void kernel_launch(void* const* d_in, const int* in_sizes, int n_in,
                              void* d_out, int out_size, void* d_ws, size_t ws_size,
                              hipStream_t stream) {
    const float* x      = (const float*)d_in[0];
    const float* qkv_w  = (const float*)d_in[1];
    const float* qkv_b  = (const float*)d_in[2];
    const float* dw_w   = (const float*)d_in[3];
    const float* dw_b   = (const float*)d_in[4];
    const float* proj_w = (const float*)d_in[5];
    const float* proj_b = (const float*)d_in[6];
    const float* temp   = (const float*)d_in[7];
    float* out = (float*)d_out;

    u16* buf1 = (u16*)d_ws;
    u16* buf2 = buf1 + (size_t)8 * 384 * 16384;

    hipFuncSetAttribute((const void*)k_qkv,  hipFuncAttributeMaxDynamicSharedMemorySize, 67584);
    hipFuncSetAttribute((const void*)k_attn, hipFuncAttributeMaxDynamicSharedMemorySize, 77824);
    hipFuncSetAttribute((const void*)k_proj, hipFuncAttributeMaxDynamicSharedMemorySize, 102400);

    k_xpose<<<dim3(128, 8), 256, 0, stream>>>(x, buf2);
    k_qkv<<<dim3(128, 3, 8), 512, 67584, stream>>>(buf2, qkv_w, qkv_b, buf1);
    k_dw<<<dim3(4, 384, 8), 256, 0, stream>>>(buf1, dw_w, dw_b, buf2);
    k_attn<<<dim3(128, 8), 512, 77824, stream>>>(buf2, temp, buf1);
    k_proj<<<dim3(128, 8), 512, 102400, stream>>>(buf1, proj_w, proj_b, out);
}